// Round 1
// baseline (297.661 us; speedup 1.0000x reference)
//
#include <hip/hip_runtime.h>
#include <hip/hip_bf16.h>
#include <math.h>

// Problem constants: B=8, H=W=128, CH=64, OC=64, NCA_C=128, K=3, dils {1,2,4,8}, HID=64
// Output: y [8,128,128,64] fp32 (8388608) then c2 [8,64] fp32 (512).

typedef float  f32x4 __attribute__((ext_vector_type(4)));
typedef short  s16x8 __attribute__((ext_vector_type(8)));

static __device__ __forceinline__ float bf2f(unsigned int u) {
    union { unsigned int i; float f; } v; v.i = u << 16; return v.f;
}
static __device__ __forceinline__ unsigned short f2bf(float f) {
    __hip_bfloat16 h = __float2bfloat16(f);
    unsigned short u; __builtin_memcpy(&u, &h, 2); return u;
}

struct F8 { float v[8]; };
static __device__ __forceinline__ F8 unp8(uint2 a, uint2 b) {
    F8 r;
    r.v[0] = bf2f(a.x & 0xffffu); r.v[1] = bf2f(a.x >> 16);
    r.v[2] = bf2f(a.y & 0xffffu); r.v[3] = bf2f(a.y >> 16);
    r.v[4] = bf2f(b.x & 0xffffu); r.v[5] = bf2f(b.x >> 16);
    r.v[6] = bf2f(b.y & 0xffffu); r.v[7] = bf2f(b.y >> 16);
    return r;
}

// ---------------- prep1: c2 = c + LN(v@Wo + bo + c), v = c@Wv + bv ----------
// (softmax pooling is exactly v since weights sum to 1 -> q/k/scores skipped)
__global__ void prep1(const float* __restrict__ c,  const float* __restrict__ Wv,
                      const float* __restrict__ bv, const float* __restrict__ Wo,
                      const float* __restrict__ bo, const float* __restrict__ lng,
                      const float* __restrict__ lnb,
                      float* __restrict__ c2f, unsigned short* __restrict__ c2b,
                      float* __restrict__ outc2)
{
    const int b = blockIdx.x, j = threadIdx.x;   // 8 blocks x 64 threads (1 wave)
    __shared__ float sc[64], sv[64];
    float cj = c[b*64 + j];
    sc[j] = cj; __syncthreads();
    float v = bv[j];
    for (int i = 0; i < 64; ++i) v += sc[i] * Wv[i*64 + j];
    sv[j] = v; __syncthreads();
    float t = bo[j] + cj;
    for (int i = 0; i < 64; ++i) t += sv[i] * Wo[i*64 + j];
    float s = t;
    for (int o = 32; o > 0; o >>= 1) s += __shfl_xor(s, o);
    float m = s * (1.f/64.f);
    float dq = (t - m) * (t - m);
    for (int o = 32; o > 0; o >>= 1) dq += __shfl_xor(dq, o);
    float var = dq * (1.f/64.f);
    float a = (t - m) / sqrtf(var + 1e-5f) * lng[j] + lnb[j];
    float c2 = cj + a;
    c2f[b*64 + j] = c2;
    c2b[b*64 + j] = f2bf(c2);
    outc2[b*64 + j] = c2;
}

// ---------------- prep2: weight swizzles + pk transpose + hidden_const ------
// W1s layout: [g(5)][kc(4)][nt(4)][lane(64)][8 bf16]  (MFMA B-frag: n=lane&15, k=kc*32+(lane>>4)*8+j)
// W2s layout: [kc(2)][nt(4)][lane(64)][8 bf16]
// pkt layout: [d(4)][tap(9)][ch(128)] bf16
// hc[b][n]  : sum over const channels (c2 identity + full-kernel-sum convs) @ W1, fp32
__global__ void prep2(const float* __restrict__ W1, const float* __restrict__ W2,
                      const float* __restrict__ pk, const float* __restrict__ c2f,
                      unsigned short* __restrict__ w1s, unsigned short* __restrict__ w2s,
                      unsigned short* __restrict__ pkt, float* __restrict__ hc)
{
    const int blk = blockIdx.x, tid = threadIdx.x;
    if (blk < 20) {
        int idx  = blk*256 + tid;                 // [0,5120)
        int lane = idx & 63, nt = (idx >> 6) & 3, kc = (idx >> 8) & 3, g = idx >> 10;
        int k0 = g*128 + kc*32 + (lane >> 4)*8;
        int n  = nt*16 + (lane & 15);
        uint4 o;
        o.x = (unsigned)f2bf(W1[(k0+0)*64+n]) | ((unsigned)f2bf(W1[(k0+1)*64+n]) << 16);
        o.y = (unsigned)f2bf(W1[(k0+2)*64+n]) | ((unsigned)f2bf(W1[(k0+3)*64+n]) << 16);
        o.z = (unsigned)f2bf(W1[(k0+4)*64+n]) | ((unsigned)f2bf(W1[(k0+5)*64+n]) << 16);
        o.w = (unsigned)f2bf(W1[(k0+6)*64+n]) | ((unsigned)f2bf(W1[(k0+7)*64+n]) << 16);
        *(uint4*)&w1s[idx*8] = o;
    } else if (blk < 22) {
        int idx  = (blk-20)*256 + tid;            // [0,512)
        int lane = idx & 63, nt = (idx >> 6) & 3, kc = idx >> 8;
        int k0 = kc*32 + (lane >> 4)*8;
        int n  = nt*16 + (lane & 15);
        uint4 o;
        o.x = (unsigned)f2bf(W2[(k0+0)*64+n]) | ((unsigned)f2bf(W2[(k0+1)*64+n]) << 16);
        o.y = (unsigned)f2bf(W2[(k0+2)*64+n]) | ((unsigned)f2bf(W2[(k0+3)*64+n]) << 16);
        o.z = (unsigned)f2bf(W2[(k0+4)*64+n]) | ((unsigned)f2bf(W2[(k0+5)*64+n]) << 16);
        o.w = (unsigned)f2bf(W2[(k0+6)*64+n]) | ((unsigned)f2bf(W2[(k0+7)*64+n]) << 16);
        *(uint4*)&w2s[idx*8] = o;
    } else if (blk == 22) {
        for (int i = tid; i < 4608; i += 256) {
            int d = i / 1152, rem = i - d*1152;
            int tap = rem >> 7, ch = rem & 127;
            pkt[i] = f2bf(pk[(d*128 + ch)*9 + tap]);   // pk[d][ch][0][ty][tx]
        }
    } else {
        for (int tix = tid; tix < 512; tix += 256) {
            int b = tix >> 6, n = tix & 63;
            float s = 0.f;
            for (int j = 0; j < 64; ++j) {
                float wsum = W1[(64+j)*64 + n];                 // identity const feature
                for (int d = 0; d < 4; ++d) {
                    float ks = 0.f;
                    for (int tp = 0; tp < 9; ++tp) ks += pk[(d*128 + 64 + j)*9 + tp];
                    wsum += ks * W1[((1+d)*128 + 64 + j)*64 + n];
                }
                s += c2f[b*64 + j] * wsum;
            }
            hc[b*64 + n] = s;
        }
    }
}

// ---------------- main fused kernel -----------------------------------------
#define XT_CS 68   // xt channel stride (64 + 4 pad: px stride 34 dwords -> 2-way banks)
#define HID_S 72   // hidden LDS stride

__global__ __launch_bounds__(256) void nca_main(
    const float* __restrict__ x,  const float* __restrict__ b1,
    const float* __restrict__ b2, const float* __restrict__ c2f,
    const unsigned short* __restrict__ c2b, const float* __restrict__ hc,
    const unsigned short* __restrict__ w1sg, const unsigned short* __restrict__ w2sg,
    const unsigned short* __restrict__ pktg, float* __restrict__ out)
{
    __shared__ unsigned short xt[24*24*XT_CS];     // 78,336 B; reused as hid[64][72]
    __shared__ unsigned short w1sl[5*2*4*64*8];    // 40,960 B (kc 0,1 only)
    __shared__ unsigned short pkl[4*9*128];        //  9,216 B

    const int tid = threadIdx.x;
    const int bi  = blockIdx.x;
    const int b   = bi >> 8;
    const int t   = bi & 255;
    const int ty0 = (t >> 4) << 3;
    const int tx0 = (t & 15) << 3;
    const bool interior = (ty0 >= 8) && (ty0 <= 112) && (tx0 >= 8) && (tx0 <= 112);

    // ---- stage x halo tile (24x24x64 fp32 -> bf16) ----
    {
        const float* xb = x + ((size_t)b * 128 * 128) * 64;
        for (int i = tid; i < 4608; i += 256) {     // 4608 = 576 px * 8 octets
            int p = i >> 3, o = i & 7;
            int r = p / 24, cc = p - r*24;
            int gy = ty0 + r - 8, gx = tx0 + cc - 8;
            uint2 lo = make_uint2(0,0), hi = make_uint2(0,0);
            if ((unsigned)gy < 128u && (unsigned)gx < 128u) {
                const float* src = xb + ((size_t)(gy*128 + gx))*64 + o*8;
                float4 f0 = *(const float4*)(src);
                float4 f1 = *(const float4*)(src + 4);
                lo.x = (unsigned)f2bf(f0.x) | ((unsigned)f2bf(f0.y) << 16);
                lo.y = (unsigned)f2bf(f0.z) | ((unsigned)f2bf(f0.w) << 16);
                hi.x = (unsigned)f2bf(f1.x) | ((unsigned)f2bf(f1.y) << 16);
                hi.y = (unsigned)f2bf(f1.z) | ((unsigned)f2bf(f1.w) << 16);
            }
            unsigned short* dst = &xt[p*XT_CS + o*8];
            *(uint2*)dst = lo;
            *(uint2*)(dst + 4) = hi;
        }
        for (int fl2 = tid; fl2 < 2560; fl2 += 256) {     // W1 frags kc<2 -> LDS
            int lane = fl2 & 63, nt = (fl2 >> 6) & 3, kc = (fl2 >> 8) & 1, g = fl2 >> 9;
            int flg = ((g*4 + kc)*4 + nt)*64 + lane;
            *(uint4*)&w1sl[fl2*8] = *(const uint4*)&w1sg[flg*8];
        }
        for (int i = tid*8; i < 4608; i += 2048)          // pk -> LDS
            *(uint4*)&pkl[i] = *(const uint4*)&pktg[i];
    }
    __syncthreads();

    const int lane = tid & 63;
    const int wv   = tid >> 6;        // wave = mtile (16 px)
    const int mr   = lane & 15;       // A row / C col index
    const int oct  = lane >> 4;       // k-octet
    const int m    = wv*16 + mr;      // pixel 0..63 in 8x8 tile
    const int ty   = m >> 3, tx = m & 7;

    f32x4 acc[4];
    #pragma unroll
    for (int nt = 0; nt < 4; ++nt) {
        float h0 = interior ? hc[b*64 + nt*16 + mr] : 0.f;
        acc[nt][0] = h0; acc[nt][1] = h0; acc[nt][2] = h0; acc[nt][3] = h0;
    }

    const int kcmax = interior ? 2 : 4;
    const int xcen  = ((ty+8)*24 + (tx+8)) * XT_CS;

    for (int g = 0; g < 5; ++g) {
        for (int kc = 0; kc < kcmax; ++kc) {
            s16x8 af;
            if (g == 0) {
                uint2 lo, hi;
                if (kc < 2) {  // identity, data channels: raw bf16 from xt
                    const unsigned short* p = &xt[xcen + kc*32 + oct*8];
                    lo = *(const uint2*)p; hi = *(const uint2*)(p + 4);
                } else {       // identity, const channels: c2 broadcast
                    const unsigned short* p = &c2b[b*64 + (kc-2)*32 + oct*8];
                    lo = *(const uint2*)p; hi = *(const uint2*)(p + 4);
                }
                af[0]=(short)(lo.x & 0xffff); af[1]=(short)(lo.x >> 16);
                af[2]=(short)(lo.y & 0xffff); af[3]=(short)(lo.y >> 16);
                af[4]=(short)(hi.x & 0xffff); af[5]=(short)(hi.x >> 16);
                af[6]=(short)(hi.y & 0xffff); af[7]=(short)(hi.y >> 16);
            } else {
                const int d = 1 << (g-1);
                float a8[8] = {0,0,0,0,0,0,0,0};
                if (kc < 2) {  // depthwise conv over staged x channels
                    const unsigned short* pkr = &pkl[(g-1)*1152 + kc*32 + oct*8];
                    const int xb0 = xcen + kc*32 + oct*8;
                    #pragma unroll
                    for (int tap = 0; tap < 9; ++tap) {
                        const int dy = tap/3 - 1, dx = tap - (tap/3)*3 - 1;
                        const unsigned short* xp = &xt[xb0 + (dy*24 + dx)*d*XT_CS];
                        F8 xv = unp8(*(const uint2*)xp, *(const uint2*)(xp + 4));
                        uint4 q = *(const uint4*)&pkr[tap*128];
                        F8 pv = unp8(make_uint2(q.x,q.y), make_uint2(q.z,q.w));
                        #pragma unroll
                        for (int j = 0; j < 8; ++j) a8[j] += xv.v[j] * pv.v[j];
                    }
                } else {       // conv of spatially-constant c2 channels (border only)
                    const unsigned short* pkr = &pkl[(g-1)*1152 + 64 + (kc-2)*32 + oct*8];
                    float s8[8] = {0,0,0,0,0,0,0,0};
                    #pragma unroll
                    for (int tap = 0; tap < 9; ++tap) {
                        const int dy = tap/3 - 1, dx = tap - (tap/3)*3 - 1;
                        int yy = ty0 + ty + dy*d, xx = tx0 + tx + dx*d;
                        float msk = (((unsigned)yy < 128u) && ((unsigned)xx < 128u)) ? 1.f : 0.f;
                        uint4 q = *(const uint4*)&pkr[tap*128];
                        F8 pv = unp8(make_uint2(q.x,q.y), make_uint2(q.z,q.w));
                        #pragma unroll
                        for (int j = 0; j < 8; ++j) s8[j] += msk * pv.v[j];
                    }
                    const float* c2p = &c2f[b*64 + (kc-2)*32 + oct*8];
                    #pragma unroll
                    for (int j = 0; j < 8; ++j) a8[j] = s8[j] * c2p[j];
                }
                #pragma unroll
                for (int j = 0; j < 8; ++j) af[j] = (short)f2bf(a8[j]);
            }
            #pragma unroll
            for (int nt = 0; nt < 4; ++nt) {
                s16x8 bf;
                if (kc < 2) bf = *(const s16x8*)&w1sl[(((g*2 + kc)*4 + nt)*64 + lane)*8];
                else        bf = *(const s16x8*)&w1sg[(((g*4 + kc)*4 + nt)*64 + lane)*8];
                acc[nt] = __builtin_amdgcn_mfma_f32_16x16x32_bf16(af, bf, acc[nt], 0, 0, 0);
            }
        }
    }

    __syncthreads();   // everyone done reading xt; reuse as hidden buffer

    unsigned short* hid = xt;   // [64][HID_S]
    #pragma unroll
    for (int nt = 0; nt < 4; ++nt) {
        float b1v = b1[nt*16 + mr];
        #pragma unroll
        for (int r = 0; r < 4; ++r) {
            float h  = acc[nt][r] + b1v;
            float gl = 0.5f * h * (1.f + erff(h * 0.70710678118654752f));
            int  mm  = wv*16 + oct*4 + r;            // C layout: row=(lane>>4)*4+reg
            hid[mm*HID_S + nt*16 + mr] = f2bf(gl);   // col = lane&15 (+16*nt)
        }
    }
    __syncthreads();   // wave writes/reads own 16 rows, but cross-lane -> barrier

    f32x4 acc2[4];
    #pragma unroll
    for (int nt = 0; nt < 4; ++nt) { acc2[nt][0]=0; acc2[nt][1]=0; acc2[nt][2]=0; acc2[nt][3]=0; }
    #pragma unroll
    for (int kc = 0; kc < 2; ++kc) {
        s16x8 a2 = *(const s16x8*)&hid[(wv*16 + mr)*HID_S + kc*32 + oct*8];
        #pragma unroll
        for (int nt = 0; nt < 4; ++nt) {
            s16x8 bf = *(const s16x8*)&w2sg[((kc*4 + nt)*64 + lane)*8];
            acc2[nt] = __builtin_amdgcn_mfma_f32_16x16x32_bf16(a2, bf, acc2[nt], 0, 0, 0);
        }
    }

    float* ob = out + ((size_t)b * 128 * 128) * 64;
    #pragma unroll
    for (int nt = 0; nt < 4; ++nt) {
        float b2v = b2[nt*16 + mr];
        #pragma unroll
        for (int r = 0; r < 4; ++r) {
            int mm = wv*16 + oct*4 + r;
            int gy = ty0 + (mm >> 3), gx = tx0 + (mm & 7);
            ob[((size_t)(gy*128 + gx))*64 + nt*16 + mr] = acc2[nt][r] + b2v;
        }
    }
}

// ---------------- launch ----------------------------------------------------
extern "C" void kernel_launch(void* const* d_in, const int* in_sizes, int n_in,
                              void* d_out, int out_size, void* d_ws, size_t ws_size,
                              hipStream_t stream) {
    const float* x   = (const float*)d_in[0];
    const float* c   = (const float*)d_in[1];
    // d_in[2..5] = Wq,bq,Wk,bk : mathematically unused (softmax weights sum to 1)
    const float* Wv  = (const float*)d_in[6];
    const float* bv  = (const float*)d_in[7];
    const float* Wo  = (const float*)d_in[8];
    const float* bo  = (const float*)d_in[9];
    const float* lng = (const float*)d_in[10];
    const float* lnb = (const float*)d_in[11];
    const float* pk  = (const float*)d_in[12];
    const float* W1  = (const float*)d_in[13];
    const float* b1  = (const float*)d_in[14];
    const float* W2  = (const float*)d_in[15];
    const float* b2  = (const float*)d_in[16];
    float* out = (float*)d_out;

    char* w = (char*)d_ws;
    float*          c2f = (float*)(w + 0);           // 2048 B
    unsigned short* c2b = (unsigned short*)(w + 2048);   // 1024 B
    float*          hcv = (float*)(w + 3072);        // 2048 B
    unsigned short* w2s = (unsigned short*)(w + 5120);   // 8192 B
    unsigned short* pkt = (unsigned short*)(w + 13312);  // 9216 B
    unsigned short* w1s = (unsigned short*)(w + 22528);  // 81920 B -> end 104448

    prep1<<<8, 64, 0, stream>>>(c, Wv, bv, Wo, bo, lng, lnb, c2f, c2b, out + 8388608);
    prep2<<<24, 256, 0, stream>>>(W1, W2, pk, c2f, w1s, w2s, pkt, hcv);
    nca_main<<<2048, 256, 0, stream>>>(x, b1, b2, c2f, c2b, hcv, w1s, w2s, pkt, out);
}

// Round 2
// 187.960 us; speedup vs baseline: 1.5836x; 1.5836x over previous
//
#include <hip/hip_runtime.h>
#include <hip/hip_bf16.h>
#include <math.h>

// B=8, H=W=128, CH=64, OC=64, NCA_C=128, K=3, dils {1,2,4,8}, HID=64
// out: y [8,128,128,64] fp32 (8388608) then c2 [8,64] fp32 (512)
//
// Strategy: depthwise conv folded into GEMM1. hidden[p] = sum over 37 positions
// (identity + 4 dils x 9 taps) of xbf[p+delta, 0:64] @ U_pos, U_pos = pk*W1 (64x64 bf16).
// Const channels (c2 broadcast) folded into hc2[b,n] with edge corrections via
// Cy/Cx tables + 4-term corner fix. GEMM2 via LDS transpose. All MFMA 16x16x32 bf16.

typedef float  f32x4 __attribute__((ext_vector_type(4)));
typedef short  s16x8 __attribute__((ext_vector_type(8)));

static __device__ __forceinline__ unsigned short f2bf(float f) {
    __hip_bfloat16 h = __float2bfloat16(f);
    unsigned short u; __builtin_memcpy(&u, &h, 2); return u;
}

// ---------------- prepA: x fp32 -> bf16 (channel-sliced layout) + c2 --------
// xbf layout: [row(b*128+y)][kcplane(4)][x(128)][16ch] bf16 (8192 shorts/row)
__global__ void prepA(const float* __restrict__ x, const float* __restrict__ c,
                      const float* __restrict__ Wv, const float* __restrict__ bv,
                      const float* __restrict__ Wo, const float* __restrict__ bo,
                      const float* __restrict__ lng, const float* __restrict__ lnb,
                      unsigned short* __restrict__ xbf, float* __restrict__ c2f,
                      float* __restrict__ outc2)
{
    const int blk = blockIdx.x, tid = threadIdx.x;
    if (blk < 2048) {
        int i = blk*256 + tid;              // [0, 524288): px = i>>2, kc = i&3
        int px = i >> 2, kc = i & 3;
        const float4* src = (const float4*)(x + (size_t)px*64 + kc*16);
        float4 f0 = src[0], f1 = src[1], f2 = src[2], f3 = src[3];
        int row = px >> 7, xc = px & 127;
        uint4 o0, o1;
        o0.x = (unsigned)f2bf(f0.x) | ((unsigned)f2bf(f0.y) << 16);
        o0.y = (unsigned)f2bf(f0.z) | ((unsigned)f2bf(f0.w) << 16);
        o0.z = (unsigned)f2bf(f1.x) | ((unsigned)f2bf(f1.y) << 16);
        o0.w = (unsigned)f2bf(f1.z) | ((unsigned)f2bf(f1.w) << 16);
        o1.x = (unsigned)f2bf(f2.x) | ((unsigned)f2bf(f2.y) << 16);
        o1.y = (unsigned)f2bf(f2.z) | ((unsigned)f2bf(f2.w) << 16);
        o1.z = (unsigned)f2bf(f3.x) | ((unsigned)f2bf(f3.y) << 16);
        o1.w = (unsigned)f2bf(f3.z) | ((unsigned)f2bf(f3.w) << 16);
        uint4* dst = (uint4*)(xbf + ((size_t)(row*4 + kc)*128 + xc)*16);
        dst[0] = o0; dst[1] = o1;
    } else {
        // c2 = c + LN(v@Wo + bo + c), v = c@Wv + bv  (softmax pool == v exactly)
        const int b = blk - 2048;
        __shared__ float sc[64], sv[64];
        const int j = tid;
        if (j < 64) sc[j] = c[b*64 + j];
        __syncthreads();
        if (j < 64) {
            float v = bv[j];
            for (int i = 0; i < 64; ++i) v += sc[i]*Wv[i*64 + j];
            sv[j] = v;
        }
        __syncthreads();
        if (j < 64) {
            float t = bo[j] + sc[j];
            for (int i = 0; i < 64; ++i) t += sv[i]*Wo[i*64 + j];
            float s = t;
            for (int o = 32; o > 0; o >>= 1) s += __shfl_xor(s, o);
            float m = s * (1.f/64.f);
            float dq = (t - m)*(t - m);
            for (int o = 32; o > 0; o >>= 1) dq += __shfl_xor(dq, o);
            float a = (t - m) / sqrtf(dq*(1.f/64.f) + 1e-5f) * lng[j] + lnb[j];
            float c2 = sc[j] + a;
            c2f[b*64 + j] = c2;
            outc2[b*64 + j] = c2;
        }
    }
}

// ---------------- prepB: U frags, W2 frags, V vectors, hcpart ---------------
// U frag idx = ((pos*2 + kc2)*4 + nt)*64 + lane ; element j <-> B[k][n],
//   k = kc2*32 + (lane>>4)*8 + j (= data channel), n = nt*16 + (lane&15)
// V[b][p][n] (p=0..35): const-channel contribution of tap p
// hcp[b][n] = b1[n] + sum_j c2[b,j]*W1[64+j][n]   (identity const part + b1)
__global__ void prepB(const float* __restrict__ pk, const float* __restrict__ W1,
                      const float* __restrict__ W2, const float* __restrict__ b1,
                      const float* __restrict__ c2f,
                      unsigned short* __restrict__ Uf, unsigned short* __restrict__ W2s,
                      float* __restrict__ V, float* __restrict__ hcp)
{
    const int blk = blockIdx.x, tid = threadIdx.x;
    if (blk < 74) {
        int idx = blk*256 + tid;            // [0, 18944) = 37*512
        int lane = idx & 63, nt = (idx >> 6) & 3, kc2 = (idx >> 8) & 1, pos = idx >> 9;
        int n  = nt*16 + (lane & 15);
        int k0 = kc2*32 + (lane >> 4)*8;
        unsigned short e[8];
        if (pos == 0) {
            #pragma unroll
            for (int j = 0; j < 8; ++j) e[j] = f2bf(W1[(k0+j)*64 + n]);
        } else {
            int di = (pos-1)/9, t = (pos-1)%9;
            #pragma unroll
            for (int j = 0; j < 8; ++j) {
                int ch = k0 + j;
                e[j] = f2bf(pk[(di*128 + ch)*9 + t] * W1[((1+di)*128 + ch)*64 + n]);
            }
        }
        uint4 o;
        o.x = (unsigned)e[0] | ((unsigned)e[1] << 16);
        o.y = (unsigned)e[2] | ((unsigned)e[3] << 16);
        o.z = (unsigned)e[4] | ((unsigned)e[5] << 16);
        o.w = (unsigned)e[6] | ((unsigned)e[7] << 16);
        *(uint4*)(Uf + (size_t)idx*8) = o;
    } else if (blk < 76) {
        int idx = (blk-74)*256 + tid;       // [0,512)
        int lane = idx & 63, nt = (idx >> 6) & 3, kc2 = (idx >> 8) & 1;
        int n  = nt*16 + (lane & 15);
        int k0 = kc2*32 + (lane >> 4)*8;
        unsigned short e[8];
        #pragma unroll
        for (int j = 0; j < 8; ++j) e[j] = f2bf(W2[(k0+j)*64 + n]);
        uint4 o;
        o.x = (unsigned)e[0] | ((unsigned)e[1] << 16);
        o.y = (unsigned)e[2] | ((unsigned)e[3] << 16);
        o.z = (unsigned)e[4] | ((unsigned)e[5] << 16);
        o.w = (unsigned)e[6] | ((unsigned)e[7] << 16);
        *(uint4*)(W2s + (size_t)idx*8) = o;
    } else if (blk < 148) {
        int idx = (blk-76)*256 + tid;       // [0, 18432) = 8*36*64
        int n = idx & 63, q = idx >> 6;     // q = b*36 + p
        int p = q % 36, b = q / 36;
        int di = p/9, t = p%9;
        float s = 0.f;
        for (int j = 0; j < 64; ++j)
            s += c2f[b*64 + j] * pk[(di*128 + 64 + j)*9 + t] * W1[((1+di)*128 + 64 + j)*64 + n];
        V[(size_t)q*64 + n] = s;
    } else {
        for (int it = tid; it < 512; it += 256) {
            int b = it >> 6, n = it & 63;
            float s = b1[n];
            for (int j = 0; j < 64; ++j) s += c2f[b*64 + j]*W1[(64 + j)*64 + n];
            hcp[it] = s;
        }
    }
}

// ---------------- main fused kernel -----------------------------------------
#define HID_S 72

__global__ __launch_bounds__(256, 2) void nca_main(
    const unsigned short* __restrict__ xbf,
    const unsigned short* __restrict__ U,
    const unsigned short* __restrict__ W2s,
    const float* __restrict__ V,
    const float* __restrict__ hcp,
    const float* __restrict__ b2,
    float* __restrict__ out)
{
    __shared__ float V_l[36*64];            //  9216 B
    __shared__ float Cx_l[16*64];           //  4096 B
    __shared__ float Cy_l[2*64];            //   512 B
    __shared__ float hc2_l[64];             //   256 B
    __shared__ unsigned short hid[256*HID_S]; // 36864 B   -> total ~51 KB

    const int tid = threadIdx.x;
    const int blk = blockIdx.x;
    const int b  = blk >> 6;
    const int y0 = (blk & 63) * 2;

    // ---- stage V, build hc2 / Cx / Cy tables ----
    {
        const float4* Vg = (const float4*)(V + (size_t)b*2304);
        for (int i = tid; i < 576; i += 256) ((float4*)V_l)[i] = Vg[i];
    }
    __syncthreads();
    for (int it = tid; it < 1024; it += 256) {      // Cx: x-edge correction
        int xi = it >> 6, n = it & 63;
        int xx = xi < 8 ? xi : 112 + xi;
        float s = 0.f;
        #pragma unroll
        for (int di = 0; di < 4; ++di) {
            int d = 1 << di;
            int dxo = (xx < d) ? 0 : ((xx >= 128 - d) ? 2 : -1);
            if (dxo >= 0) {
                s += V_l[(di*9 + 0*3 + dxo)*64 + n];
                s += V_l[(di*9 + 1*3 + dxo)*64 + n];
                s += V_l[(di*9 + 2*3 + dxo)*64 + n];
            }
        }
        Cx_l[it] = s;
    }
    for (int it = tid; it < 128; it += 256) {       // Cy: y-edge correction (this block's rows)
        int r = it >> 6, n = it & 63;
        int yy = y0 + r;
        float s = 0.f;
        #pragma unroll
        for (int di = 0; di < 4; ++di) {
            int d = 1 << di;
            int dyo = (yy < d) ? 0 : ((yy >= 128 - d) ? 2 : -1);
            if (dyo >= 0) {
                s += V_l[(di*9 + dyo*3 + 0)*64 + n];
                s += V_l[(di*9 + dyo*3 + 1)*64 + n];
                s += V_l[(di*9 + dyo*3 + 2)*64 + n];
            }
        }
        Cy_l[it] = s;
    }
    if (tid < 64) {                                  // hc2 = hcpart + sum_all V
        float s = hcp[b*64 + tid];
        for (int p = 0; p < 36; ++p) s += V_l[p*64 + tid];
        hc2_l[tid] = s;
    }
    __syncthreads();

    // ---- geometry ----
    const int lane = tid & 63;
    const int w    = tid >> 6;          // wave id: row = y0 + (w>>1), x-half = (w&1)*64
    const int y    = y0 + (w >> 1);
    const int xw   = (w & 1) * 64;
    const int ln15 = lane & 15;
    const int oct  = lane >> 4;

    const unsigned short* xb_lane = xbf + (size_t)b*1048576 + (oct >> 1)*2048 + (oct & 1)*8;

    f32x4 acc[4][4];
    #pragma unroll
    for (int mt = 0; mt < 4; ++mt)
        #pragma unroll
        for (int nt = 0; nt < 4; ++nt) {
            acc[mt][nt][0] = 0.f; acc[mt][nt][1] = 0.f;
            acc[mt][nt][2] = 0.f; acc[mt][nt][3] = 0.f;
        }

    const s16x8 z8 = {0,0,0,0,0,0,0,0};

    auto process = [&](int pos, int yy, int dx) {
        const unsigned short* rowp = xb_lane + (size_t)yy*8192;
        int xq = xw + ln15 + dx;
        int xc_[4]; bool vm[4];
        #pragma unroll
        for (int mt = 0; mt < 4; ++mt) {
            int xm = xq + mt*16;
            vm[mt] = (unsigned)xm < 128u;
            xc_[mt] = (xm < 0) ? 0 : (xm > 127 ? 127 : xm);
        }
        #pragma unroll
        for (int kc2 = 0; kc2 < 2; ++kc2) {
            s16x8 av[4];
            #pragma unroll
            for (int mt = 0; mt < 4; ++mt) {
                s16x8 t = *(const s16x8*)(rowp + kc2*4096 + xc_[mt]*16);
                av[mt] = vm[mt] ? t : z8;
            }
            const unsigned short* Up = U + (size_t)pos*4096 + kc2*2048 + lane*8;
            #pragma unroll
            for (int nt = 0; nt < 4; ++nt) {
                s16x8 bf = *(const s16x8*)(Up + nt*512);
                #pragma unroll
                for (int mt = 0; mt < 4; ++mt)
                    acc[mt][nt] = __builtin_amdgcn_mfma_f32_16x16x32_bf16(av[mt], bf, acc[mt][nt], 0, 0, 0);
            }
        }
    };

    process(0, y, 0);                       // identity position
    for (int di = 0; di < 4; ++di) {
        const int d = 1 << di;
        for (int dyi = 0; dyi < 3; ++dyi) {
            int yy = y + (dyi - 1)*d;
            if ((unsigned)yy >= 128u) continue;   // data contribution is zero (SAME pad)
            for (int dxi = 0; dxi < 3; ++dxi)
                process(1 + di*9 + dyi*3 + dxi, yy, (dxi - 1)*d);
        }
    }

    // ---- epilogue 1: + hc2 - corrections, GELU, write hid (bf16) ----
    const bool yedge = (y < 8) || (y >= 120);
    #pragma unroll
    for (int mt = 0; mt < 4; ++mt) {
        #pragma unroll
        for (int nt = 0; nt < 4; ++nt) {
            const int n = nt*16 + ln15;
            const float hcv = hc2_l[n];
            const float cyv = yedge ? Cy_l[(w >> 1)*64 + n] : 0.f;
            #pragma unroll
            for (int r = 0; r < 4; ++r) {
                int m = oct*4 + r;                  // C row = (lane>>4)*4 + reg
                int x = xw + mt*16 + m;
                float h = acc[mt][nt][r] + hcv - cyv;
                if (x < 8 || x >= 120) {
                    int xi = (x < 8) ? x : (x - 112);
                    h -= Cx_l[xi*64 + n];
                    if (yedge) {                    // corner double-subtract fix
                        #pragma unroll
                        for (int di = 0; di < 4; ++di) {
                            int d = 1 << di;
                            int dyo = (y < d) ? 0 : ((y >= 128 - d) ? 2 : -1);
                            int dxo = (x < d) ? 0 : ((x >= 128 - d) ? 2 : -1);
                            if (dyo >= 0 && dxo >= 0)
                                h += V_l[(di*9 + dyo*3 + dxo)*64 + n];
                        }
                    }
                }
                // GELU (tanh approx, max abs err ~3e-4; threshold is 0.136)
                float u = 0.7978845608028654f * (h + 0.044715f*h*h*h);
                float g = h / (1.f + __expf(-2.f*u));
                hid[(w*64 + mt*16 + m)*HID_S + n] = f2bf(g);
            }
        }
    }
    // no __syncthreads needed: each wave reads back only its own 64 hid rows

    // ---- GEMM2: y = hid @ W2 + b2 ----
    f32x4 acc2[4][4];
    #pragma unroll
    for (int mt = 0; mt < 4; ++mt)
        #pragma unroll
        for (int nt = 0; nt < 4; ++nt) {
            acc2[mt][nt][0] = 0.f; acc2[mt][nt][1] = 0.f;
            acc2[mt][nt][2] = 0.f; acc2[mt][nt][3] = 0.f;
        }
    #pragma unroll
    for (int kc2 = 0; kc2 < 2; ++kc2) {
        s16x8 a2[4];
        #pragma unroll
        for (int mt = 0; mt < 4; ++mt)
            a2[mt] = *(const s16x8*)&hid[(w*64 + mt*16 + ln15)*HID_S + kc2*32 + oct*8];
        #pragma unroll
        for (int nt = 0; nt < 4; ++nt) {
            s16x8 bf = *(const s16x8*)(W2s + ((size_t)(kc2*4 + nt)*64 + lane)*8);
            #pragma unroll
            for (int mt = 0; mt < 4; ++mt)
                acc2[mt][nt] = __builtin_amdgcn_mfma_f32_16x16x32_bf16(a2[mt], bf, acc2[mt][nt], 0, 0, 0);
        }
    }

    float* ob = out + ((size_t)(b*128 + y))*128*64;
    #pragma unroll
    for (int nt = 0; nt < 4; ++nt) {
        const float b2v = b2[nt*16 + ln15];
        #pragma unroll
        for (int mt = 0; mt < 4; ++mt) {
            #pragma unroll
            for (int r = 0; r < 4; ++r) {
                int x = xw + mt*16 + oct*4 + r;
                ob[(size_t)x*64 + nt*16 + ln15] = acc2[mt][nt][r] + b2v;
            }
        }
    }
}

// ---------------- launch ----------------------------------------------------
extern "C" void kernel_launch(void* const* d_in, const int* in_sizes, int n_in,
                              void* d_out, int out_size, void* d_ws, size_t ws_size,
                              hipStream_t stream) {
    const float* x   = (const float*)d_in[0];
    const float* c   = (const float*)d_in[1];
    // d_in[2..5] = Wq,bq,Wk,bk : unused (softmax weights sum to 1 -> pool == v)
    const float* Wv  = (const float*)d_in[6];
    const float* bv  = (const float*)d_in[7];
    const float* Wo  = (const float*)d_in[8];
    const float* bo  = (const float*)d_in[9];
    const float* lng = (const float*)d_in[10];
    const float* lnb = (const float*)d_in[11];
    const float* pk  = (const float*)d_in[12];
    const float* W1  = (const float*)d_in[13];
    const float* b1  = (const float*)d_in[14];
    const float* W2  = (const float*)d_in[15];
    const float* b2  = (const float*)d_in[16];
    float* out = (float*)d_out;

    char* w = (char*)d_ws;
    unsigned short* xbf = (unsigned short*)(w);                  // 16,777,216 B
    unsigned short* Uf  = (unsigned short*)(w + 16777216);       //    303,104 B
    unsigned short* W2s = (unsigned short*)(w + 17080320);       //      8,192 B
    float*          V   = (float*)         (w + 17088512);       //     73,728 B
    float*          hcp = (float*)         (w + 17162240);       //      2,048 B
    float*          c2f = (float*)         (w + 17164288);       //      2,048 B  (end 17,166,336)

    prepA<<<2056, 256, 0, stream>>>(x, c, Wv, bv, Wo, bo, lng, lnb, xbf, c2f, out + 8388608);
    prepB<<<149, 256, 0, stream>>>(pk, W1, W2, b1, c2f, Uf, W2s, V, hcp);
    nca_main<<<512, 256, 0, stream>>>(xbf, Uf, W2s, V, hcp, b2, out);
}